// Round 3
// baseline (250.343 us; speedup 1.0000x reference)
//
#include <hip/hip_runtime.h>
#include <hip/hip_bf16.h>

#define BB   16
#define EMB  768
#define CIN  64
#define COUT 64
#define HH   112
#define WW   112
#define HID  192
#define TOTAL 36864                 // COUT*CIN*9
#define KSZ  576                    // CIN*9
#define PW   114                    // padded H/W

typedef short bf16x8 __attribute__((ext_vector_type(8)));
typedef float f32x4  __attribute__((ext_vector_type(4)));
typedef int   i32x4  __attribute__((ext_vector_type(4)));

static __device__ __forceinline__ unsigned short f2bf(float f) {
    unsigned u = __float_as_uint(f);
    u += 0x7FFF + ((u >> 16) & 1);          // RNE
    return (unsigned short)(u >> 16);
}

// ---------------- Kernel A: h = relu(cls @ W1 + b1)  (16 x 192) ----------------
__global__ void mlp1_kernel(const float* __restrict__ cls, const float* __restrict__ W1,
                            const float* __restrict__ b1, float* __restrict__ h) {
    __shared__ float xs[EMB];
    const int b = blockIdx.x;
    const int j = threadIdx.x;                 // 0..191
    for (int k = j; k < EMB; k += HID) xs[k] = cls[b * EMB + k];
    __syncthreads();
    float acc = b1[j];
    #pragma unroll 8
    for (int k = 0; k < EMB; ++k) acc += xs[k] * W1[k * HID + j];
    h[b * HID + j] = fmaxf(acc, 0.f);
}

// ---- Kernel B: params = tanh(h @ W2 + b2), written bf16 as A[b][p9][co][ci] ----
__global__ __launch_bounds__(256) void mlp2_kernel(const float* __restrict__ h,
                                                   const float* __restrict__ W2,
                                                   const float* __restrict__ b2,
                                                   unsigned short* __restrict__ Ag) {
    __shared__ float hs[BB * HID];
    const int tid = threadIdx.x;
    for (int i = tid; i < BB * HID; i += 256) hs[i] = h[i];
    __syncthreads();
    const int t = blockIdx.x * 256 + tid;      // 0..36863 (grid = 144 exact)
    float acc[BB];
    const float bias = b2[t];
    #pragma unroll
    for (int b = 0; b < BB; ++b) acc[b] = bias;
    for (int k = 0; k < HID; ++k) {
        const float w = W2[k * TOTAL + t];
        #pragma unroll
        for (int b = 0; b < BB; ++b) acc[b] += hs[b * HID + k] * w;
    }
    // t = co*576 + ci*9 + p9   ->   Ag[((b*9 + p9)*64 + co)*64 + ci]
    const int co  = t / KSZ;
    const int rem = t - co * KSZ;
    const int ci  = rem / 9;
    const int p9  = rem - ci * 9;
    #pragma unroll
    for (int b = 0; b < BB; ++b) {
        const size_t o = (((size_t)b * 9 + p9) * 64 + co) * 64 + ci;
        Ag[o] = f2bf(tanhf(acc[b]));
    }
}

// ---- Pre-pass: feat NCHW fp32 -> zero-padded NHWC bf16  P[b][py][px][64] ----
__global__ __launch_bounds__(256) void prepass_kernel(const float* __restrict__ feat,
                                                      unsigned short* __restrict__ P) {
    const int py  = blockIdx.x;                // 0..113
    const int b   = blockIdx.y;
    const int tid = threadIdx.x;
    unsigned short* Prow = P + ((size_t)b * PW + py) * PW * 64;

    if (py == 0 || py == PW - 1) {             // zero full halo row (14592 B)
        i32x4 z = {0, 0, 0, 0};
        i32x4* p4 = (i32x4*)Prow;
        for (int i = tid; i < PW * 64 * 2 / 16; i += 256) p4[i] = z;
        return;
    }
    const int y = py - 1;
    // zero x-halo columns px=0 and px=113 (128 B each)
    if (tid < 32)            ((int*)Prow)[tid] = 0;
    else if (tid < 64)       ((int*)(Prow + (size_t)(PW - 1) * 64))[tid - 32] = 0;

    const int ck = tid & 7;                    // ci chunk (8 ci each)
    const int xs = tid >> 3;                   // 0..31
    for (int xc = 0; xc < 4; ++xc) {
        const int x = xc * 32 + xs;
        if (x < WW) {
            const float* fp = feat + (((size_t)b * CIN + ck * 8) * HH + y) * WW + x;
            unsigned short tmp[8];
            #pragma unroll
            for (int j = 0; j < 8; ++j) tmp[j] = f2bf(fp[(size_t)j * HH * WW]);
            *(bf16x8*)(Prow + (size_t)(x + 1) * 64 + ck * 8) = *(bf16x8*)tmp;
        }
    }
}

// ---------------- Conv: LDS-free MFMA implicit GEMM + residual ----------------
// Block: 256 thr / 4 waves; wave = co-tile (16 co). Block does 2 rows x 112 px.
#define RR 2
__global__ __launch_bounds__(256) void conv_kernel(const float* __restrict__ feat,
                                                   const unsigned short* __restrict__ Ag,
                                                   const unsigned short* __restrict__ P,
                                                   float* __restrict__ out) {
    const int tid  = threadIdx.x;
    const int b    = blockIdx.y;
    const int y0   = blockIdx.x * RR;
    const int wave = tid >> 6;                 // co-tile 0..3
    const int lane = tid & 63;
    const int lg   = lane >> 4;
    const int ln   = lane & 15;

    // A-fragments for this wave's 16 co: loaded once, reused for both rows
    const unsigned short* Ab = Ag + (size_t)b * 9 * 64 * 64;
    bf16x8 af[9][2];
    #pragma unroll
    for (int p9 = 0; p9 < 9; ++p9)
        #pragma unroll
        for (int cib = 0; cib < 2; ++cib)
            af[p9][cib] = *(const bf16x8*)(Ab + (size_t)(p9 * 64 + wave * 16 + ln) * 64
                                           + cib * 32 + lg * 8);

    const unsigned short* Pb = P + (size_t)b * PW * PW * 64;

    for (int r = 0; r < RR; ++r) {
        const int y = y0 + r;
        f32x4 acc[7];
        #pragma unroll
        for (int t = 0; t < 7; ++t) acc[t] = (f32x4){0.f, 0.f, 0.f, 0.f};

        #pragma unroll
        for (int p9 = 0; p9 < 9; ++p9) {
            const int kh = p9 / 3, kw = p9 - 3 * kh;
            // padded row = y+kh, padded col for (t,ln) = t*16 + ln + kw
            const unsigned short* pk = Pb + ((size_t)(y + kh) * PW + ln + kw) * 64;
            #pragma unroll
            for (int cib = 0; cib < 2; ++cib) {
                const unsigned short* pc = pk + cib * 32 + lg * 8;
                #pragma unroll
                for (int t = 0; t < 7; ++t) {
                    bf16x8 bf = *(const bf16x8*)(pc + (size_t)t * 16 * 64);
                    acc[t] = __builtin_amdgcn_mfma_f32_16x16x32_bf16(af[p9][cib], bf, acc[t], 0, 0, 0);
                }
            }
        }

        // epilogue: D col=ln=pixel, row=lg*4+rg=co_local; residual add
        #pragma unroll
        for (int t = 0; t < 7; ++t) {
            const int x = t * 16 + ln;
            #pragma unroll
            for (int rg = 0; rg < 4; ++rg) {
                const int co = wave * 16 + lg * 4 + rg;
                const size_t o = (((size_t)b * COUT + co) * HH + y) * WW + x;
                out[o] = acc[t][rg] + feat[o];
            }
        }
    }
}

extern "C" void kernel_launch(void* const* d_in, const int* in_sizes, int n_in,
                              void* d_out, int out_size, void* d_ws, size_t ws_size,
                              hipStream_t stream) {
    const float* cls      = (const float*)d_in[0];
    const float* features = (const float*)d_in[1];
    const float* W1       = (const float*)d_in[2];
    const float* b1       = (const float*)d_in[3];
    const float* W2       = (const float*)d_in[4];
    const float* b2       = (const float*)d_in[5];
    float* out = (float*)d_out;

    float*          h  = (float*)d_ws;                       // 12 KB
    unsigned short* Ag = (unsigned short*)(h + BB * HID);    // 1.18 MB
    unsigned short* P  = Ag + (size_t)BB * 9 * 64 * 64;      // 26.6 MB padded NHWC bf16

    mlp1_kernel<<<BB, HID, 0, stream>>>(cls, W1, b1, h);
    mlp2_kernel<<<TOTAL / 256, 256, 0, stream>>>(h, W2, b2, Ag);
    prepass_kernel<<<dim3(PW, BB), 256, 0, stream>>>(features, P);
    conv_kernel<<<dim3(HH / RR, BB), 256, 0, stream>>>(features, Ag, P, out);
}

// Round 4
// 74.918 us; speedup vs baseline: 3.3415x; 3.3415x over previous
//
#include <hip/hip_runtime.h>
#include <hip/hip_bf16.h>

#define BB   16
#define EMB  768
#define CIN  64
#define COUT 64
#define HH   112
#define WW   112
#define HID  192
#define TOTAL 36864                 // COUT*CIN*9
#define KSZ  576                    // CIN*9
#define PW   114                    // padded H/W
#define ROWB (PW * 64 * 2)          // 14592 B: one padded row, NHWC bf16

typedef short bf16x8 __attribute__((ext_vector_type(8)));
typedef float f32x4  __attribute__((ext_vector_type(4)));
typedef int   i32x4  __attribute__((ext_vector_type(4)));

static __device__ __forceinline__ unsigned short f2bf(float f) {
    unsigned u = __float_as_uint(f);
    u += 0x7FFF + ((u >> 16) & 1);          // RNE
    return (unsigned short)(u >> 16);
}

#define GLOAD_LDS16(g, l) \
    __builtin_amdgcn_global_load_lds((const __attribute__((address_space(1))) void*)(g), \
                                     (__attribute__((address_space(3))) void*)(l), 16, 0, 0)

// ---------------- Kernel A: h = relu(cls @ W1 + b1), k-split 4 ----------------
__global__ __launch_bounds__(768) void mlp1_kernel(const float* __restrict__ cls,
                                                   const float* __restrict__ W1,
                                                   const float* __restrict__ b1,
                                                   float* __restrict__ h) {
    __shared__ float xs[EMB];
    __shared__ float red[3 * HID];
    const int b   = blockIdx.x;
    const int tid = threadIdx.x;
    xs[tid] = cls[b * EMB + tid];
    __syncthreads();
    const int j  = tid % HID;
    const int kq = tid / HID;
    float acc = 0.f;
    #pragma unroll 8
    for (int k = kq * 192; k < kq * 192 + 192; ++k) acc += xs[k] * W1[k * HID + j];
    if (kq) red[(kq - 1) * HID + j] = acc;
    __syncthreads();
    if (kq == 0)
        h[b * HID + j] = fmaxf(acc + red[j] + red[HID + j] + red[2 * HID + j] + b1[j], 0.f);
}

// ---- Kernel B: params = tanh(h @ W2 + b2) (+ identity at center tap),
//      written bf16 as A[b][p9][co][ci].  Grid 576 x 256thr, 4 b per thread. ----
__global__ __launch_bounds__(256) void mlp2_kernel(const float* __restrict__ h,
                                                   const float* __restrict__ W2,
                                                   const float* __restrict__ b2,
                                                   unsigned short* __restrict__ Ag) {
    __shared__ float hs[BB * HID];
    const int tid = threadIdx.x;
    for (int i = tid; i < BB * HID; i += 256) hs[i] = h[i];
    __syncthreads();
    const int t  = blockIdx.x * 64 + (tid & 63);   // 0..36863
    const int bq = tid >> 6;                        // b-quarter
    float acc[4];
    const float bias = b2[t];
    #pragma unroll
    for (int q = 0; q < 4; ++q) acc[q] = bias;
    const float* hb = hs + bq * 4 * HID;
    #pragma unroll 8
    for (int k = 0; k < HID; ++k) {
        const float w = W2[(size_t)k * TOTAL + t];
        #pragma unroll
        for (int q = 0; q < 4; ++q) acc[q] += hb[q * HID + k] * w;
    }
    // t = co*576 + ci*9 + p9 ; fold residual: A[center] += I
    const int co  = t / KSZ;
    const int rem = t - co * KSZ;
    const int ci  = rem / 9;
    const int p9  = rem - ci * 9;
    const float idv = (p9 == 4 && co == ci) ? 1.f : 0.f;
    #pragma unroll
    for (int q = 0; q < 4; ++q) {
        const int b = bq * 4 + q;
        Ag[(((size_t)b * 9 + p9) * 64 + co) * 64 + ci] = f2bf(tanhf(acc[q]) + idv);
    }
}

// ---- Pre-pass: feat NCHW fp32 -> zero-padded NHWC bf16  P[b][py][px][64] ----
__global__ __launch_bounds__(256) void prepass_kernel(const float* __restrict__ feat,
                                                      unsigned short* __restrict__ P) {
    __shared__ unsigned short ts[WW * 72];          // [x][ci], stride 72 el (16B-aligned)
    const int py  = blockIdx.x;                     // 0..113
    const int b   = blockIdx.y;
    const int tid = threadIdx.x;
    unsigned short* Prow = P + ((size_t)b * PW + py) * (PW * 64);

    if (py == 0 || py == PW - 1) {                  // zero full halo row
        i32x4 z = {0, 0, 0, 0};
        for (int i = tid; i < ROWB / 16; i += 256) ((i32x4*)Prow)[i] = z;
        return;
    }
    const int y = py - 1;
    // zero x-halo cells px=0, px=113 (128 B each)
    if (tid < 8)       ((i32x4*)Prow)[tid] = (i32x4){0, 0, 0, 0};
    else if (tid < 16) ((i32x4*)(Prow + (size_t)(PW - 1) * 64))[tid - 8] = (i32x4){0, 0, 0, 0};

    // phase 1: coalesced NCHW read, transpose into LDS [x][ci]
    const float* fb = feat + (size_t)b * CIN * HH * WW + (size_t)y * WW;
    for (int i = tid; i < CIN * WW; i += 256) {
        const int ci = i / WW, x = i - ci * WW;
        ts[x * 72 + ci] = f2bf(fb[(size_t)ci * HH * WW + x]);
    }
    __syncthreads();
    // phase 2: coalesced 16-B NHWC writes
    for (int j = tid; j < WW * 8; j += 256) {
        const int x = j >> 3, g = j & 7;
        *(bf16x8*)(Prow + (size_t)(x + 1) * 64 + g * 8) = *(const bf16x8*)(ts + x * 72 + g * 8);
    }
}

// ---------------- Conv: MFMA implicit GEMM, LDS-staged B, identity-fused ----------------
// Block: 256 thr / 4 waves (wave = 16-co tile), 2 output rows x 112 px.
// LDS: 4 padded rows [s][col][64ci], chunk-XOR swizzle g' = g ^ (col&7).
__global__ __launch_bounds__(256) void conv_kernel(const unsigned short* __restrict__ Ag,
                                                   const unsigned short* __restrict__ P,
                                                   float* __restrict__ out) {
    __shared__ __align__(16) char lds[4 * ROWB];    // 58368 B
    const int tid  = threadIdx.x;
    const int b    = blockIdx.y;
    const int y0   = blockIdx.x * 2;
    const int wave = tid >> 6;
    const int lane = tid & 63;
    const int lg   = lane >> 4;
    const int ln   = lane & 15;

    // A-fragments (16 co x 9 taps x 64 ci), issued early; L2-resident
    const unsigned short* Ab = Ag + (size_t)b * 9 * 4096;
    bf16x8 af[9][2];
    #pragma unroll
    for (int p9 = 0; p9 < 9; ++p9)
        #pragma unroll
        for (int cib = 0; cib < 2; ++cib)
            af[p9][cib] = *(const bf16x8*)(Ab + (size_t)(p9 * 64 + wave * 16 + ln) * 64
                                           + cib * 32 + lg * 8);

    // stage padded rows y0..y0+3 via global_load_lds, inverse-swizzled source
    const char* Prow0 = (const char*)(P + ((size_t)b * PW + y0) * (PW * 64));
    #pragma unroll
    for (int it = 0; it < 14; ++it) {
        const int i = it * 256 + tid;               // chunk 0..3583
        const int s = i / 912;
        const int j = i - s * 912;
        const int c = j >> 3, g = j & 7;
        GLOAD_LDS16(Prow0 + (size_t)s * ROWB + c * 128 + ((g ^ (c & 7)) << 4),
                    lds + (size_t)i * 16);
    }
    if (tid < 64) {                                 // chunks 3584..3647 (full wave 0)
        const int i = 3584 + tid;
        const int j = i - 3 * 912;
        const int c = j >> 3, g = j & 7;
        GLOAD_LDS16(Prow0 + (size_t)3 * ROWB + c * 128 + ((g ^ (c & 7)) << 4),
                    lds + (size_t)i * 16);
    }
    __syncthreads();

    #pragma unroll
    for (int r = 0; r < 2; ++r) {
        f32x4 acc[7];
        #pragma unroll
        for (int t = 0; t < 7; ++t) acc[t] = (f32x4){0.f, 0.f, 0.f, 0.f};

        #pragma unroll
        for (int p9 = 0; p9 < 9; ++p9) {
            const int kh = p9 / 3, kw = p9 - 3 * kh;
            const char* lbase = lds + (r + kh) * ROWB + (ln + kw) * 128;
            const int   c7    = (ln + kw) & 7;
            #pragma unroll
            for (int cib = 0; cib < 2; ++cib) {
                const int sw = ((cib * 4 + lg) ^ c7) << 4;
                #pragma unroll
                for (int t = 0; t < 7; ++t) {
                    const bf16x8 bf = *(const bf16x8*)(lbase + t * 2048 + sw);
                    acc[t] = __builtin_amdgcn_mfma_f32_16x16x32_bf16(af[p9][cib], bf, acc[t], 0, 0, 0);
                }
            }
        }

        // epilogue: pure stores (residual already folded into A)
        const int y = y0 + r;
        float* ob = out + (((size_t)b * COUT + wave * 16 + lg * 4) * HH + y) * WW + ln;
        #pragma unroll
        for (int t = 0; t < 7; ++t)
            #pragma unroll
            for (int rg = 0; rg < 4; ++rg)
                ob[(size_t)rg * HH * WW + t * 16] = acc[t][rg];
    }
}

extern "C" void kernel_launch(void* const* d_in, const int* in_sizes, int n_in,
                              void* d_out, int out_size, void* d_ws, size_t ws_size,
                              hipStream_t stream) {
    const float* cls      = (const float*)d_in[0];
    const float* features = (const float*)d_in[1];
    const float* W1       = (const float*)d_in[2];
    const float* b1       = (const float*)d_in[3];
    const float* W2       = (const float*)d_in[4];
    const float* b2       = (const float*)d_in[5];
    float* out = (float*)d_out;

    float*          h  = (float*)d_ws;                       // 12 KB
    unsigned short* Ag = (unsigned short*)(h + BB * HID);    // 1.18 MB
    unsigned short* P  = Ag + (size_t)BB * 9 * 4096;         // 26.6 MB padded NHWC bf16

    mlp1_kernel<<<BB, 768, 0, stream>>>(cls, W1, b1, h);
    mlp2_kernel<<<TOTAL / 64, 256, 0, stream>>>(h, W2, b2, Ag);
    prepass_kernel<<<dim3(PW, BB), 256, 0, stream>>>(features, P);
    conv_kernel<<<dim3(HH / 2, BB), 256, 0, stream>>>(Ag, P, out);
}

// Round 5
// 74.590 us; speedup vs baseline: 3.3563x; 1.0044x over previous
//
#include <hip/hip_runtime.h>
#include <hip/hip_bf16.h>

#define BB   16
#define EMB  768
#define CIN  64
#define COUT 64
#define HH   112
#define WW   112
#define HID  192
#define TOTAL 36864                 // COUT*CIN*9
#define KSZ  576                    // CIN*9
#define PW   114                    // padded H/W
#define ROWB (PW * 64 * 2)          // 14592 B: one padded row, NHWC bf16

typedef short bf16x8 __attribute__((ext_vector_type(8)));
typedef float f32x4  __attribute__((ext_vector_type(4)));
typedef int   i32x4  __attribute__((ext_vector_type(4)));

static __device__ __forceinline__ unsigned short f2bf(float f) {
    unsigned u = __float_as_uint(f);
    u += 0x7FFF + ((u >> 16) & 1);          // RNE
    return (unsigned short)(u >> 16);
}

#define GLOAD_LDS16(g, l) \
    __builtin_amdgcn_global_load_lds((const __attribute__((address_space(1))) void*)(g), \
                                     (__attribute__((address_space(3))) void*)(l), 16, 0, 0)

// ---------------- Kernel A: h = relu(cls @ W1 + b1), k-split 4 ----------------
__global__ __launch_bounds__(768) void mlp1_kernel(const float* __restrict__ cls,
                                                   const float* __restrict__ W1,
                                                   const float* __restrict__ b1,
                                                   float* __restrict__ h) {
    __shared__ float xs[EMB];
    __shared__ float red[3 * HID];
    const int b   = blockIdx.x;
    const int tid = threadIdx.x;
    xs[tid] = cls[b * EMB + tid];
    __syncthreads();
    const int j  = tid % HID;
    const int kq = tid / HID;
    float acc = 0.f;
    #pragma unroll 8
    for (int k = kq * 192; k < kq * 192 + 192; ++k) acc += xs[k] * W1[k * HID + j];
    if (kq) red[(kq - 1) * HID + j] = acc;
    __syncthreads();
    if (kq == 0)
        h[b * HID + j] = fmaxf(acc + red[j] + red[HID + j] + red[2 * HID + j] + b1[j], 0.f);
}

// ---- Kernel B: params = tanh(h @ W2 + b2) (+ identity at center tap),
//      written bf16 as A[b][p9][co][ci].  Grid 576 x 256thr, 4 b per thread. ----
__global__ __launch_bounds__(256) void mlp2_kernel(const float* __restrict__ h,
                                                   const float* __restrict__ W2,
                                                   const float* __restrict__ b2,
                                                   unsigned short* __restrict__ Ag) {
    __shared__ float hs[BB * HID];
    const int tid = threadIdx.x;
    for (int i = tid; i < BB * HID; i += 256) hs[i] = h[i];
    __syncthreads();
    const int t  = blockIdx.x * 64 + (tid & 63);   // 0..36863
    const int bq = tid >> 6;                        // b-quarter
    float acc[4];
    const float bias = b2[t];
    #pragma unroll
    for (int q = 0; q < 4; ++q) acc[q] = bias;
    const float* hb = hs + bq * 4 * HID;
    #pragma unroll 8
    for (int k = 0; k < HID; ++k) {
        const float w = W2[(size_t)k * TOTAL + t];
        #pragma unroll
        for (int q = 0; q < 4; ++q) acc[q] += hb[q * HID + k] * w;
    }
    // t = co*576 + ci*9 + p9 ; fold residual: A[center] += I
    const int co  = t / KSZ;
    const int rem = t - co * KSZ;
    const int ci  = rem / 9;
    const int p9  = rem - ci * 9;
    const float idv = (p9 == 4 && co == ci) ? 1.f : 0.f;
    #pragma unroll
    for (int q = 0; q < 4; ++q) {
        const int b = bq * 4 + q;
        Ag[(((size_t)b * 9 + p9) * 64 + co) * 64 + ci] = f2bf(tanhf(acc[q]) + idv);
    }
}

// ---- Pre-pass: feat NCHW fp32 -> zero-padded NHWC bf16  P[b][py][px][64] ----
__global__ __launch_bounds__(256) void prepass_kernel(const float* __restrict__ feat,
                                                      unsigned short* __restrict__ P) {
    __shared__ unsigned short ts[WW * 72];          // [x][ci], stride 72 el
    const int py  = blockIdx.x;                     // 0..113
    const int b   = blockIdx.y;
    const int tid = threadIdx.x;
    unsigned short* Prow = P + ((size_t)b * PW + py) * (PW * 64);

    if (py == 0 || py == PW - 1) {                  // zero full halo row
        i32x4 z = {0, 0, 0, 0};
        for (int i = tid; i < ROWB / 16; i += 256) ((i32x4*)Prow)[i] = z;
        return;
    }
    const int y = py - 1;
    // zero x-halo cells px=0, px=113 (128 B each)
    if (tid < 8)       ((i32x4*)Prow)[tid] = (i32x4){0, 0, 0, 0};
    else if (tid < 16) ((i32x4*)(Prow + (size_t)(PW - 1) * 64))[tid - 8] = (i32x4){0, 0, 0, 0};

    // phase 1: coalesced NCHW reads, 2 ci per thread -> one b32 LDS write
    const float* fb = feat + (size_t)b * CIN * HH * WW + (size_t)y * WW;
    #pragma unroll
    for (int it = 0; it < 14; ++it) {
        const int i = it * 256 + tid;               // 0..3583 = 32 ci-pairs x 112 x
        const int p = i / WW;
        const int x = i - p * WW;
        const float va = fb[(size_t)(2 * p) * HH * WW + x];
        const float vb = fb[(size_t)(2 * p + 1) * HH * WW + x];
        const unsigned pk = (unsigned)f2bf(va) | ((unsigned)f2bf(vb) << 16);
        *(unsigned*)(ts + (size_t)x * 72 + 2 * p) = pk;
    }
    __syncthreads();
    // phase 2: coalesced 16-B NHWC writes
    for (int j = tid; j < WW * 8; j += 256) {
        const int x = j >> 3, g = j & 7;
        *(bf16x8*)(Prow + (size_t)(x + 1) * 64 + g * 8) = *(const bf16x8*)(ts + x * 72 + g * 8);
    }
}

// -------- Conv: MFMA implicit GEMM, LDS-staged B, identity-fused residual --------
// Block: 256 thr / 4 waves; wave = (co-half, out-row).  Block: 64 co x 2 rows x 112 px.
// Each B-fragment ds_read feeds 2 MFMAs (2 co-tiles per wave).
// LDS: 4 padded rows [s][col][64ci], chunk-XOR swizzle g' = g ^ (col&7).
__global__ __launch_bounds__(256) void conv_kernel(const unsigned short* __restrict__ Ag,
                                                   const unsigned short* __restrict__ P,
                                                   float* __restrict__ out) {
    __shared__ __align__(16) char lds[4 * ROWB];    // 58368 B
    const int tid = threadIdx.x;
    // XCD-chunked swizzle: each XCD owns 112 consecutive logical blocks (= 2 batches)
    const int bid  = (blockIdx.x & 7) * 112 + (blockIdx.x >> 3);
    const int b    = bid / 56;
    const int tile = bid - b * 56;
    const int y0   = tile * 2;
    const int wave = tid >> 6;
    const int lane = tid & 63;
    const int cog  = wave & 1;                      // co half (32 co)
    const int r    = wave >> 1;                     // output row 0/1
    const int lg   = lane >> 4;
    const int ln   = lane & 15;

    // stage padded rows y0..y0+3 via global_load_lds, inverse-swizzled source
    const char* Prow0 = (const char*)(P + ((size_t)b * PW + y0) * (PW * 64));
    #pragma unroll
    for (int it = 0; it < 14; ++it) {
        const int i = it * 256 + tid;               // chunk 0..3583
        const int s = i / 912;
        const int j = i - s * 912;
        const int c = j >> 3, g = j & 7;
        GLOAD_LDS16(Prow0 + (size_t)s * ROWB + c * 128 + ((g ^ (c & 7)) << 4),
                    lds + (size_t)i * 16);
    }
    if (tid < 64) {                                 // chunks 3584..3647
        const int i = 3584 + tid;
        const int j = i - 3 * 912;
        const int c = j >> 3, g = j & 7;
        GLOAD_LDS16(Prow0 + (size_t)3 * ROWB + c * 128 + ((g ^ (c & 7)) << 4),
                    lds + (size_t)i * 16);
    }

    // A-fragments for this wave's 32 co x 9 taps x 64 ci, fully preloaded
    const unsigned short* Ab = Ag + (size_t)b * 9 * 4096;
    bf16x8 af[9][2][2];
    #pragma unroll
    for (int p9 = 0; p9 < 9; ++p9)
        #pragma unroll
        for (int ct = 0; ct < 2; ++ct)
            #pragma unroll
            for (int cib = 0; cib < 2; ++cib)
                af[p9][ct][cib] = *(const bf16x8*)(Ab + (size_t)(p9 * 64 + cog * 32 + ct * 16 + ln) * 64
                                                   + cib * 32 + lg * 8);
    __syncthreads();

    f32x4 acc[2][7];
    #pragma unroll
    for (int ct = 0; ct < 2; ++ct)
        #pragma unroll
        for (int t = 0; t < 7; ++t) acc[ct][t] = (f32x4){0.f, 0.f, 0.f, 0.f};

    #pragma unroll
    for (int p9 = 0; p9 < 9; ++p9) {
        const int kh = p9 / 3, kw = p9 - 3 * kh;
        const char* lbase = lds + (r + kh) * ROWB + (ln + kw) * 128;
        const int   c7    = (ln + kw) & 7;
        #pragma unroll
        for (int cib = 0; cib < 2; ++cib) {
            const int sw = ((cib * 4 + lg) ^ c7) << 4;
            #pragma unroll
            for (int t = 0; t < 7; ++t) {
                const bf16x8 bf = *(const bf16x8*)(lbase + t * 2048 + sw);
                acc[0][t] = __builtin_amdgcn_mfma_f32_16x16x32_bf16(af[p9][0][cib], bf, acc[0][t], 0, 0, 0);
                acc[1][t] = __builtin_amdgcn_mfma_f32_16x16x32_bf16(af[p9][1][cib], bf, acc[1][t], 0, 0, 0);
            }
        }
    }

    // epilogue: pure stores (residual folded into A)
    const int y = y0 + r;
    float* ob = out + (((size_t)b * COUT + cog * 32 + lg * 4) * HH + y) * WW + ln;
    #pragma unroll
    for (int ct = 0; ct < 2; ++ct)
        #pragma unroll
        for (int t = 0; t < 7; ++t)
            #pragma unroll
            for (int rg = 0; rg < 4; ++rg)
                ob[((size_t)(ct * 16 + rg)) * HH * WW + t * 16] = acc[ct][t][rg];
}

extern "C" void kernel_launch(void* const* d_in, const int* in_sizes, int n_in,
                              void* d_out, int out_size, void* d_ws, size_t ws_size,
                              hipStream_t stream) {
    const float* cls      = (const float*)d_in[0];
    const float* features = (const float*)d_in[1];
    const float* W1       = (const float*)d_in[2];
    const float* b1       = (const float*)d_in[3];
    const float* W2       = (const float*)d_in[4];
    const float* b2       = (const float*)d_in[5];
    float* out = (float*)d_out;

    float*          h  = (float*)d_ws;                       // 12 KB
    unsigned short* Ag = (unsigned short*)(h + BB * HID);    // 1.18 MB
    unsigned short* P  = Ag + (size_t)BB * 9 * 4096;         // 26.6 MB padded NHWC bf16

    mlp1_kernel<<<BB, 768, 0, stream>>>(cls, W1, b1, h);
    mlp2_kernel<<<TOTAL / 64, 256, 0, stream>>>(h, W2, b2, Ag);
    prepass_kernel<<<dim3(PW, BB), 256, 0, stream>>>(features, P);
    conv_kernel<<<56 * BB, 256, 0, stream>>>(Ag, P, out);
}